// Round 12
// baseline (84.621 us; speedup 1.0000x reference)
//
#include <hip/hip_runtime.h>
#include <hip/hip_bf16.h>
#include <stdint.h>

#define M_DIM 2048
#define K_DIM 4096
#define N_DIM 4096

typedef __attribute__((ext_vector_type(8))) short short8;
typedef __attribute__((ext_vector_type(4))) float f32x4;

#define MFMA __builtin_amdgcn_mfma_f32_16x16x32_bf16

// RNE float -> bf16, packed pair
__device__ __forceinline__ uint32_t bf16pk(float a, float b) {
  uint32_t ua = __float_as_uint(a);
  ua = (ua + 0x7FFFu + ((ua >> 16) & 1u)) >> 16;
  uint32_t ub = __float_as_uint(b);
  ub = (ub + 0x7FFFu + ((ub >> 16) & 1u)) >> 16;
  return ua | (ub << 16);
}

__device__ __forceinline__ void glds16(const char* g, char* l) {
  __builtin_amdgcn_global_load_lds((__attribute__((address_space(1))) void*)g,
                                   (__attribute__((address_space(3))) void*)l, 16, 0, 0);
}

// ---------------------------------------------------------------------------
// Image layout: BK=32 steps, 8KB tiles, [k8-slot 0..3][row 0..127][16B].
//  xImg[mt 0..15][step 0..127]  (16.78 MB): x[mt*128+row][step*32+slot*8+e]
//  wImg[nt 0..31][step 0..127]  (33.55 MB): W[step*32+slot*8+e][nt*128+col]
// Verified R6-R11 (0 bank conflicts; index algebra checked).
// ---------------------------------------------------------------------------

// Merged prepass (R8-verified bodies): grid 3072 x 256.
__global__ void __launch_bounds__(256) prep_kernel(const float* __restrict__ x,
                                                   const uint32_t* __restrict__ qweight,
                                                   const uint32_t* __restrict__ qzeros,
                                                   const float* __restrict__ scales,
                                                   char* __restrict__ xImg,
                                                   char* __restrict__ wImg) {
  const int tid = threadIdx.x;
  if (blockIdx.x < 1024) {
    const int bid = blockIdx.x;
    const int mt = bid >> 6, ktp = bid & 63;
    const int row = tid & 127, sh = tid >> 7;
    const int s = ktp * 2 + sh;
    const float* src = x + (size_t)(mt * 128 + row) * K_DIM + s * 32;
    char* dst = xImg + (size_t)(mt * 128 + s) * 8192 + row * 16;
#pragma unroll
    for (int slot = 0; slot < 4; ++slot) {
      float4 f0 = *(const float4*)(src + slot * 8);
      float4 f1 = *(const float4*)(src + slot * 8 + 4);
      uint4 pk;
      pk.x = bf16pk(f0.x, f0.y);
      pk.y = bf16pk(f0.z, f0.w);
      pk.z = bf16pk(f1.x, f1.y);
      pk.w = bf16pk(f1.z, f1.w);
      *(uint4*)(dst + slot * 2048) = pk;
    }
  } else {
    const int bid = blockIdx.x - 1024;
    const int nt = bid >> 6, ktp = bid & 63;
    const int n = tid & 127, sh = tid >> 7;
    const int s = ktp * 2 + sh;
    const int g = ktp >> 1;                    // group = 128 k = 4 steps
    const int gn = nt * 128 + n;
    uint32_t zq = qzeros[g * (N_DIM / 8) + (gn >> 3)];
    const int z = (int)((zq >> ((gn & 7) * 4)) & 15u) + 1;
    const float s_ = scales[g * N_DIM + gn];
    char* dst = wImg + (size_t)(nt * 128 + s) * 8192 + n * 16;
#pragma unroll
    for (int slot = 0; slot < 4; ++slot) {
      uint32_t q = qweight[(size_t)(s * 4 + slot) * N_DIM + gn];
      float f[8];
#pragma unroll
      for (int v = 0; v < 8; ++v) {
        int w = (int)((q >> (4 * v)) & 15u);
        f[v] = (float)(w - z) * s_;            // exact int sub, cvt, mul
      }
      uint4 pk;
      pk.x = bf16pk(f[0], f[1]);
      pk.y = bf16pk(f[2], f[3]);
      pk.z = bf16pk(f[4], f[5]);
      pk.w = bf16pk(f[6], f[7]);
      *(uint4*)(dst + slot * 2048) = pk;
    }
  }
}

// ---------------------------------------------------------------------------
// GEMM: ring-3 + one-step-early ds_reads (pipe-overlap fix).
// BM=128, BN=256, 8 waves (2ks x 4wc), per-wave 128x64 (R8-verified frag
// geometry), in-block K-split, grid 256 = 1 block/CU, LDS 3 x 48KB = 144KB.
//
// Why: R8-R11 all show LDS-read pipe and MFMA pipe SERIALIZING (1256
// cyc/step = 620 MFMA + 576 reads + writes) because reads issue after the
// step barrier. Here each wave issues reads(t+1) BEFORE MFMA(t); its 12
// reads drain under its own MFMA cluster; counted lgkmcnt(12) crosses the
// barrier (T3/T4).
//
// Ledger per step t (slots (t)%3=compute, (t+1)%3=read-early, (t+2)%3=stage):
//   reads(t+1): legal -- stage(t+1) drained by ALL waves (own vmcnt(0)
//     end-of-(t-1)) + barrier(end t-1); slot not written this step.
//   STAGE(t+2): overwrites step-(t-1) slot; its reads completed (lgkm
//     before MFMA(t-1)) + barrier(end t-1).
//   lgkmcnt(12): outstanding = reads(t+1) newest 12 -> reads(t) complete.
//   vmcnt(0): drains own STAGE(t+2) (issued ~1200 cyc earlier) BEFORE the
//     barrier (R7 race-fix pattern).
// Tail: t=62 no stage; t=63 no reads, lgkmcnt(0), no barrier.
// ---------------------------------------------------------------------------
__global__ void __launch_bounds__(512, 1) gemm_kernel(const char* __restrict__ xImg,
                                                      const char* __restrict__ wImg,
                                                      const float* __restrict__ bias,
                                                      float* __restrict__ out) {
  __shared__ uint4 ldsv[9216];                 // 147456 B = 3 slots x 48KB
  char* lds = (char*)ldsv;
  const int tid = threadIdx.x;
  const int lane = tid & 63, wid = tid >> 6;
  const int ks = wid >> 2, wc = wid & 3;       // 2 ks-halves x 4 N-quarters
  const int lr = lane & 15, lk = lane >> 4;

  // XCD swizzle: xcd = bid&7 owns nb pair {2x,2x+1} (4MB B = L2) x all mb
  const int bid = blockIdx.x;                  // 256 blocks
  const int local = bid >> 3, xcd = bid & 7;
  const int nb = xcd * 2 + (local & 1);        // 0..15
  const int mb = local >> 1;                   // 0..15

  f32x4 acc[8][4];
#pragma unroll
  for (int i = 0; i < 8; ++i)
#pragma unroll
    for (int j = 0; j < 4; ++j) acc[i][j] = f32x4{0.f, 0.f, 0.f, 0.f};

  const char* aT = xImg + (size_t)mb * 128 * 8192;          // steps 0..127
  const char* bT0 = wImg + (size_t)(2 * nb) * 128 * 8192;   // cols 0-127
  const char* bT1 = wImg + (size_t)(2 * nb + 1) * 128 * 8192; // cols 128-255

  // slot layout (48KB): A0[0,8K) A1[8K,16K) B0h0[16K) B0h1[24K) B1h0[32K) B1h1[40K)
  int aoff[8], boff[4];
#pragma unroll
  for (int i = 0; i < 8; ++i) aoff[i] = ks * 8192 + lk * 2048 + (i * 16 + lr) * 16;
#pragma unroll
  for (int j = 0; j < 4; ++j)
    boff[j] = 16384 + ks * 16384 + (wc >> 1) * 8192 + lk * 2048 +
              ((wc & 1) * 64 + j * 16 + lr) * 16;

#define STAGE(T, SLOT)                                                     \
  do {                                                                     \
    char* d = lds + (SLOT) * 49152;                                        \
    glds16(aT + (size_t)(T) * 8192 + tid * 16, d + tid * 16);              \
    glds16(aT + (size_t)(64 + (T)) * 8192 + tid * 16, d + 8192 + tid * 16);\
    glds16(bT0 + (size_t)(T) * 8192 + tid * 16, d + 16384 + tid * 16);     \
    glds16(bT1 + (size_t)(T) * 8192 + tid * 16, d + 24576 + tid * 16);     \
    glds16(bT0 + (size_t)(64 + (T)) * 8192 + tid * 16, d + 32768 + tid * 16);\
    glds16(bT1 + (size_t)(64 + (T)) * 8192 + tid * 16, d + 40960 + tid * 16);\
  } while (0)

  short8 vA[2][8], vB[2][4];

  // prologue: stage slot0, drain, bar; reads(0); stage slot1, drain, bar
  STAGE(0, 0);
  asm volatile("s_waitcnt vmcnt(0)" ::: "memory");
  __builtin_amdgcn_sched_barrier(0);
  __builtin_amdgcn_s_barrier();
#pragma unroll
  for (int i = 0; i < 8; ++i) vA[0][i] = *(const short8*)(lds + aoff[i]);
#pragma unroll
  for (int j = 0; j < 4; ++j) vB[0][j] = *(const short8*)(lds + boff[j]);
  STAGE(1, 1);
  asm volatile("s_waitcnt vmcnt(0)" ::: "memory");
  __builtin_amdgcn_sched_barrier(0);
  __builtin_amdgcn_s_barrier();

#pragma unroll 2
  for (int t = 0; t < 64; ++t) {
    const int cs = t & 1, ns = cs ^ 1;

    // 1. reads(t+1) -- early, drains under this step's MFMA
    if (t < 63) {
      const char* rbuf = lds + ((t + 1) % 3) * 49152;
#pragma unroll
      for (int i = 0; i < 8; ++i) vA[ns][i] = *(const short8*)(rbuf + aoff[i]);
#pragma unroll
      for (int j = 0; j < 4; ++j) vB[ns][j] = *(const short8*)(rbuf + boff[j]);
    }
    // 2. stage(t+2)
    if (t < 62) STAGE(t + 2, (t + 2) % 3);
    __builtin_amdgcn_sched_barrier(0);

    // 3. counted wait: reads(t) complete (12 newest = reads(t+1) in flight)
    if (t < 63) asm volatile("s_waitcnt lgkmcnt(12)" ::: "memory");
    else        asm volatile("s_waitcnt lgkmcnt(0)" ::: "memory");
    __builtin_amdgcn_sched_barrier(0);

    __builtin_amdgcn_s_setprio(1);
#pragma unroll
    for (int j = 0; j < 4; ++j) {
#pragma unroll
      for (int i = 0; i < 8; ++i)
        acc[i][j] = MFMA(vA[cs][i], vB[cs][j], acc[i][j], 0, 0, 0);
    }
    __builtin_amdgcn_s_setprio(0);

    if (t < 63) {
      asm volatile("s_waitcnt vmcnt(0)" ::: "memory");   // own stage(t+2) landed
      __builtin_amdgcn_sched_barrier(0);
      __builtin_amdgcn_s_barrier();                      // globalize
    }
  }
#undef STAGE

  // ---- epilogue: in-block cross-ks reduction via LDS exchange ----
  // (R8-verified structure; wc now 0..3 -> 64KB per side)
  __syncthreads();   // all K-loop LDS reads done; ring space free
  if (ks == 1) {
#pragma unroll
    for (int i = 0; i < 4; ++i)
#pragma unroll
      for (int j = 0; j < 4; ++j)
        *(f32x4*)(lds + (wc * 16 + i * 4 + j) * 1024 + lane * 16) = acc[i][j];
  } else {
#pragma unroll
    for (int i = 4; i < 8; ++i)
#pragma unroll
      for (int j = 0; j < 4; ++j)
        *(f32x4*)(lds + 65536 + (wc * 16 + (i - 4) * 4 + j) * 1024 + lane * 16) = acc[i][j];
  }
  __syncthreads();

  // C/D map col=lane&15, row=(lane>>4)*4+reg (verified R0-R11)
  const int colB = nb * 256 + wc * 64 + lr;
  if (ks == 0) {
#pragma unroll
    for (int j = 0; j < 4; ++j) {
      int col = colB + j * 16;
      float bj = bias[col];
#pragma unroll
      for (int i = 0; i < 4; ++i) {
        f32x4 p = *(const f32x4*)(lds + (wc * 16 + i * 4 + j) * 1024 + lane * 16);
        int row = mb * 128 + i * 16 + lk * 4;
#pragma unroll
        for (int r = 0; r < 4; ++r)
          out[(size_t)(row + r) * N_DIM + col] = acc[i][j][r] + p[r] + bj;
      }
    }
  } else {
#pragma unroll
    for (int j = 0; j < 4; ++j) {
      int col = colB + j * 16;
      float bj = bias[col];
#pragma unroll
      for (int i = 4; i < 8; ++i) {
        f32x4 p = *(const f32x4*)(lds + 65536 + (wc * 16 + (i - 4) * 4 + j) * 1024 + lane * 16);
        int row = mb * 128 + i * 16 + lk * 4;
#pragma unroll
        for (int r = 0; r < 4; ++r)
          out[(size_t)(row + r) * N_DIM + col] = acc[i][j][r] + p[r] + bj;
      }
    }
  }
}

// ---------------------------------------------------------------------------
// Fallback (workspace too small)
// ---------------------------------------------------------------------------
__global__ void fallback_kernel(const float* __restrict__ x, const uint32_t* __restrict__ qweight,
                                const uint32_t* __restrict__ qzeros, const float* __restrict__ scales,
                                const float* __restrict__ bias, float* __restrict__ out) {
  __shared__ float xs[16][17];
  __shared__ float ws[16][17];
  int tx = threadIdx.x, ty = threadIdx.y;
  int col = blockIdx.x * 16 + tx;
  int row = blockIdx.y * 16 + ty;
  float acc = 0.f;
  for (int k0 = 0; k0 < K_DIM; k0 += 16) {
    xs[ty][tx] = x[(size_t)row * K_DIM + k0 + tx];
    int k = k0 + ty;
    int g = k >> 7;
    uint32_t q = qweight[(size_t)(k >> 3) * N_DIM + col];
    int w = (int)((q >> ((k & 7) * 4)) & 15u);
    uint32_t zq = qzeros[g * (N_DIM / 8) + (col >> 3)];
    int z = (int)((zq >> ((col & 7) * 4)) & 15u) + 1;
    ws[ty][tx] = (float)(w - z) * scales[g * N_DIM + col];
    __syncthreads();
#pragma unroll
    for (int kk = 0; kk < 16; ++kk) acc += xs[ty][kk] * ws[kk][tx];
    __syncthreads();
  }
  out[(size_t)row * N_DIM + col] = acc + bias[col];
}

extern "C" void kernel_launch(void* const* d_in, const int* in_sizes, int n_in,
                              void* d_out, int out_size, void* d_ws, size_t ws_size,
                              hipStream_t stream) {
  const float* x = (const float*)d_in[0];
  const uint32_t* qweight = (const uint32_t*)d_in[1];
  const uint32_t* qzeros = (const uint32_t*)d_in[2];
  const float* scales = (const float*)d_in[3];
  // d_in[4] = g_idx (== arange(K)//128, folded into index math)
  const float* bias = (const float*)d_in[5];
  float* out = (float*)d_out;

  const size_t X_IMG = (size_t)16 * 128 * 8192;   // 16.78 MB
  const size_t W_IMG = (size_t)32 * 128 * 8192;   // 33.55 MB

  if (ws_size >= X_IMG + W_IMG) {
    char* xImg = (char*)d_ws;
    char* wImg = (char*)d_ws + X_IMG;
    prep_kernel<<<3072, 256, 0, stream>>>(x, qweight, qzeros, scales, xImg, wImg);
    gemm_kernel<<<256, 512, 0, stream>>>(xImg, wImg, bias, out);
  } else {
    fallback_kernel<<<dim3(N_DIM / 16, M_DIM / 16), dim3(16, 16), 0, stream>>>(
        x, qweight, qzeros, scales, bias, out);
  }
}